// Round 9
// baseline (307.855 us; speedup 1.0000x reference)
//
#include <hip/hip_runtime.h>

#define IMH 512
#define IMW 512
#define BATCH 8
#define NTOK 20480
#define NC 4096
#define NF 16384
#define ED 128

typedef float vf4 __attribute__((ext_vector_type(4)));

__device__ __forceinline__ void nt_store4(float* p, float a, float b, float c, float d) {
    vf4 v = {a, b, c, d};
    __builtin_nontemporal_store(v, (vf4*)p);
}
__device__ __forceinline__ void nt_store4v(float* p, float4 v) {
    nt_store4(p, v.x, v.y, v.z, v.w);
}

// ============ DIAGNOSTIC ROUND: single-role kernels, idempotent rep-loops ===
// Rep factors push each dispatch above the ~52us harness fills so all three
// roles appear in top-5 WITH counters. Outputs are bit-identical to R8.

// ---- coarse: 1024 blocks, 32 patches/block, wave-uniform scalar loads -----
__global__ __launch_bounds__(256) void k_coarse(const float* __restrict__ x,
                                                const float* __restrict__ wc,
                                                const float* __restrict__ bc,
                                                const float* __restrict__ temb,
                                                float* __restrict__ out) {
    int blk = blockIdx.x;
    int t = threadIdx.x;
    int lane = t & 63;
    for (int rep = 0; rep < 6; ++rep) {
        asm volatile("" ::: "memory");
        int b = blk >> 7;
        int pblk = (blk & 127) * 32;
        int wv = __builtin_amdgcn_readfirstlane(t >> 6);  // wave id 0..3
        int h = wv & 1;
        int p0 = pblk + (wv >> 1) * 16;
        int d = h * 64 + lane;
        float wcol[64];
        #pragma unroll
        for (int k = 0; k < 64; ++k) wcol[k] = wc[k * ED + d];
        float base = bc[d] + temb[d];
        const float* img = x + ((size_t)b * IMH + (p0 >> 6) * 8) * IMW + (p0 & 63) * 8;
        float* dst = out + ((size_t)b * NTOK + p0) * ED + d;
        #pragma unroll
        for (int p = 0; p < 16; ++p) {
            const float* pimg = img + p * 8;    // wave-uniform -> scalar loads
            float acc = base;
            #pragma unroll
            for (int r = 0; r < 8; ++r) {
                const float* rp = pimg + r * IMW;
                acc += rp[0] * wcol[r * 8 + 0] + rp[1] * wcol[r * 8 + 1]
                     + rp[2] * wcol[r * 8 + 2] + rp[3] * wcol[r * 8 + 3]
                     + rp[4] * wcol[r * 8 + 4] + rp[5] * wcol[r * 8 + 5]
                     + rp[6] * wcol[r * 8 + 6] + rp[7] * wcol[r * 8 + 7];
            }
            __builtin_nontemporal_store(acc, dst + (size_t)p * ED);
        }
    }
}

// ---- edge: 512 blocks, one 64x64 tile -> 16x16 fp64 cells + tile sum ------
__global__ __launch_bounds__(256) void k_edge(const float* __restrict__ x,
                                              double* __restrict__ edges,
                                              double* __restrict__ tsum) {
    __shared__ float esm[66][68];
    __shared__ double dred[4];
    int blk = blockIdx.x;
    int t = threadIdx.x;
    int lane = t & 63, wid = t >> 6;
    for (int rep = 0; rep < 8; ++rep) {
        asm volatile("" ::: "memory");
        int b = blk >> 6;
        int tile = blk & 63;
        int ty0 = (tile >> 3) * 64;
        int tx0 = (tile & 7) * 64;
        const float* img = x + (size_t)b * (IMH * IMW);
        for (int idx = t; idx < 66 * 66; idx += 256) {
            int r = idx / 66, c = idx - r * 66;
            int gy = ty0 - 1 + r, gx = tx0 - 1 + c;
            float v = 0.f;
            if (gy >= 0 && gy < IMH && gx >= 0 && gx < IMW) v = img[gy * IMW + gx];
            esm[r][c] = v;
        }
        __syncthreads();
        int cy = t >> 4, cx = t & 15;
        double acc = 0.0;
        #pragma unroll
        for (int dy = 0; dy < 4; ++dy) {
            int py = cy * 4 + dy + 1;
            #pragma unroll
            for (int dx = 0; dx < 4; ++dx) {
                int px = cx * 4 + dx + 1;
                double a00 = (double)esm[py - 1][px - 1];
                double a01 = (double)esm[py - 1][px];
                double a02 = (double)esm[py - 1][px + 1];
                double a10 = (double)esm[py][px - 1];
                double a12 = (double)esm[py][px + 1];
                double a20 = (double)esm[py + 1][px - 1];
                double a21 = (double)esm[py + 1][px];
                double a22 = (double)esm[py + 1][px + 1];
                double sx = (a02 + 2.0 * a12 + a22) - (a00 + 2.0 * a10 + a20);
                double sy = (a20 + 2.0 * a21 + a22) - (a00 + 2.0 * a01 + a02);
                acc += sqrt(sx * sx + sy * sy);
            }
        }
        double cell = acc * (1.0 / 16.0);
        int gy = (ty0 >> 2) + cy;
        int gx = (tx0 >> 2) + cx;
        edges[((size_t)b << 14) + gy * 128 + gx] = cell;
        double sc = cell;
        #pragma unroll
        for (int off = 32; off > 0; off >>= 1) sc += __shfl_xor(sc, off);
        if (lane == 0) dred[wid] = sc;
        __syncthreads();
        if (t == 0) tsum[b * 64 + tile] = dred[0] + dred[1] + dred[2] + dred[3];
        __syncthreads();
    }
}

// ---- fine: grid (128,8), one patch-row/block, self-sufficient prefix ------
__global__ __launch_bounds__(256) void k_fine(const float* __restrict__ x,
                                              const float* __restrict__ wfp,
                                              const float* __restrict__ bfp,
                                              const float* __restrict__ temb,
                                              const double* __restrict__ edges,
                                              const double* __restrict__ tsum,
                                              float* __restrict__ out,
                                              float* __restrict__ mask_out) {
    int b = blockIdx.y;
    int row = blockIdx.x;
    int t = threadIdx.x;
    int lane = t & 63, wid = t >> 6;
    __shared__ float smx[4][512];
    __shared__ int excl_s[256];
    __shared__ unsigned long long bits_s[256];
    __shared__ int wtot[4];
    for (int rep = 0; rep < 6; ++rep) {
        asm volatile("" ::: "memory");
        __syncthreads();
        const double* ts = tsum + b * 64;
        double total = 0.0;
        #pragma unroll
        for (int j = 0; j < 64; ++j) total += ts[j];
        double mean = total * (1.0 / 16384.0);

        const double* e = edges + ((size_t)b << 14) + t * 64;
        unsigned long long mybits = 0ULL;
        #pragma unroll
        for (int j = 0; j < 32; ++j) {
            double2 dv = *(const double2*)&e[j * 2];
            if (dv.x > mean) mybits |= (1ULL << (2 * j));
            if (dv.y > mean) mybits |= (1ULL << (2 * j + 1));
        }
        int cnt = __popcll(mybits);
        int incl = cnt;
        #pragma unroll
        for (int off = 1; off < 64; off <<= 1) {
            int up = __shfl_up(incl, off);
            if (lane >= off) incl += up;
        }
        if (lane == 63) wtot[wid] = incl;
        bits_s[t] = mybits;
        __syncthreads();
        int woff = 0, K = 0;
        #pragma unroll
        for (int w = 0; w < 4; ++w) { int c = wtot[w]; K += c; if (w < wid) woff += c; }
        excl_s[t] = woff + incl - cnt;

        const float* img = x + ((size_t)b * IMH + row * 4) * IMW;
        #pragma unroll
        for (int k = 0; k < 2; ++k) {
            int idx = t + 256 * k;
            int r = idx >> 7, c4 = idx & 127;
            *(float4*)&smx[r][c4 * 4] = *(const float4*)&img[r * IMW + c4 * 4];
        }
        __syncthreads();

        int base = excl_s[2 * row];
        unsigned long long lo = bits_s[2 * row];
        unsigned long long hi = bits_s[2 * row + 1];

        if (t < 128) {
            unsigned long long bb = (t < 64) ? lo : hi;
            float mv = ((bb >> (t & 63)) & 1ULL) ? 1.0f : 0.0f;
            __builtin_nontemporal_store(mv, mask_out + ((size_t)b << 14) + row * 128 + t);
        }

        int d4 = t & 31;
        int g = t >> 5;
        float4 wcol[16];
        #pragma unroll
        for (int k = 0; k < 16; ++k) wcol[k] = *(const float4*)&wfp[k * ED + d4 * 4];
        float4 fill = *(const float4*)&temb[ED + d4 * 4];
        float4 bse = *(const float4*)&bfp[d4 * 4];
        float4 fbase = make_float4(bse.x + fill.x, bse.y + fill.y, bse.z + fill.z, bse.w + fill.w);
        float* tok = out + ((size_t)b * NTOK + NC) * ED;
        int i0 = row * 128;
        #pragma unroll
        for (int pp = 0; pp < 16; ++pp) {
            int p = g + pp * 8;
            int i = i0 + p;
            unsigned long long bb = (p < 64) ? lo : hi;
            if ((bb >> (p & 63)) & 1ULL) {
                int below = (p < 64)
                    ? __popcll(lo & ((1ULL << p) - 1))
                    : __popcll(lo) + __popcll(hi & ((1ULL << (p - 64)) - 1));
                int ps = base + below;
                float4 acc = fbase;
                #pragma unroll
                for (int r = 0; r < 4; ++r) {
                    float4 vv = *(const float4*)&smx[r][p * 4];
                    acc.x += vv.x * wcol[4 * r].x + vv.y * wcol[4 * r + 1].x + vv.z * wcol[4 * r + 2].x + vv.w * wcol[4 * r + 3].x;
                    acc.y += vv.x * wcol[4 * r].y + vv.y * wcol[4 * r + 1].y + vv.z * wcol[4 * r + 2].y + vv.w * wcol[4 * r + 3].y;
                    acc.z += vv.x * wcol[4 * r].z + vv.y * wcol[4 * r + 1].z + vv.z * wcol[4 * r + 2].z + vv.w * wcol[4 * r + 3].z;
                    acc.w += vv.x * wcol[4 * r].w + vv.y * wcol[4 * r + 1].w + vv.z * wcol[4 * r + 2].w + vv.w * wcol[4 * r + 3].w;
                }
                nt_store4v(tok + ((size_t)ps * 32 + d4) * 4, acc);
            }
            if (i >= K) {
                nt_store4v(tok + ((size_t)i * 32 + d4) * 4, fill);
            }
        }
        __syncthreads();
    }
}

extern "C" void kernel_launch(void* const* d_in, const int* in_sizes, int n_in,
                              void* d_out, int out_size, void* d_ws, size_t ws_size,
                              hipStream_t stream) {
    const float* x    = (const float*)d_in[0];
    const float* wc   = (const float*)d_in[1];
    const float* bc   = (const float*)d_in[2];
    const float* wfp  = (const float*)d_in[3];
    const float* bfp  = (const float*)d_in[4];
    const float* temb = (const float*)d_in[5];
    float* out = (float*)d_out;

    char* wsb = (char*)d_ws;
    double* edges = (double*)wsb;                              // 1 MiB
    double* tsum  = (double*)(wsb + (size_t)BATCH * NF * 8);   // 4 KiB
    float* mask_out = out + (size_t)BATCH * NTOK * ED;

    k_edge<<<dim3(512), 256, 0, stream>>>(x, edges, tsum);
    k_coarse<<<dim3(1024), 256, 0, stream>>>(x, wc, bc, temb, out);
    k_fine<<<dim3(128, BATCH), 256, 0, stream>>>(x, wfp, bfp, temb, edges, tsum, out, mask_out);
}

// Round 10
// 58.756 us; speedup vs baseline: 5.2396x; 5.2396x over previous
//
#include <hip/hip_runtime.h>

#define IMH 512
#define IMW 512
#define BATCH 8
#define NTOK 20480
#define NC 4096
#define NF 16384
#define ED 128

typedef float vf4 __attribute__((ext_vector_type(4)));

__device__ __forceinline__ void nt_store4v(float* p, float4 v) {
    vf4 t = {v.x, v.y, v.z, v.w};
    __builtin_nontemporal_store(t, (vf4*)p);
}

// ---------------- Kernel 1: coarse embed (blocks 0-1023) + edge map (1024-1535)
__global__ __launch_bounds__(256) void k1_edge_coarse(const float* __restrict__ x,
                                                      const float* __restrict__ wc,
                                                      const float* __restrict__ bc,
                                                      const float* __restrict__ temb,
                                                      float* __restrict__ out,
                                                      double* __restrict__ edges,
                                                      double* __restrict__ tsum) {
    __shared__ float esm[66][68];
    __shared__ double dred[4];
    int blk = blockIdx.x;
    int t = threadIdx.x;
    int lane = t & 63, wid = t >> 6;
    if (blk < 1024) {
        // ---- coarse role: 32 patches/block, wave-uniform scalar loads, no LDS
        int b = blk >> 7;
        int pblk = (blk & 127) * 32;
        int wv = __builtin_amdgcn_readfirstlane(t >> 6);
        int h = wv & 1;
        int p0 = pblk + (wv >> 1) * 16;
        int d = h * 64 + lane;
        float wcol[64];
        #pragma unroll
        for (int k = 0; k < 64; ++k) wcol[k] = wc[k * ED + d];
        float base = bc[d] + temb[d];
        const float* img = x + ((size_t)b * IMH + (p0 >> 6) * 8) * IMW + (p0 & 63) * 8;
        float* dst = out + ((size_t)b * NTOK + p0) * ED + d;
        #pragma unroll
        for (int p = 0; p < 16; ++p) {
            const float* pimg = img + p * 8;    // wave-uniform -> scalar loads
            float acc = base;
            #pragma unroll
            for (int r = 0; r < 8; ++r) {
                const float* rp = pimg + r * IMW;
                acc += rp[0] * wcol[r * 8 + 0] + rp[1] * wcol[r * 8 + 1]
                     + rp[2] * wcol[r * 8 + 2] + rp[3] * wcol[r * 8 + 3]
                     + rp[4] * wcol[r * 8 + 4] + rp[5] * wcol[r * 8 + 5]
                     + rp[6] * wcol[r * 8 + 6] + rp[7] * wcol[r * 8 + 7];
            }
            __builtin_nontemporal_store(acc, dst + (size_t)p * ED);
        }
    } else {
        // ---- edge role: one 64x64 tile -> 16x16 fp64 cells + fp64 tile sum
        int blk2 = blk - 1024;
        int b = blk2 >> 6;
        int tile = blk2 & 63;
        int ty0 = (tile >> 3) * 64;
        int tx0 = (tile & 7) * 64;
        const float* img = x + (size_t)b * (IMH * IMW);
        for (int idx = t; idx < 66 * 66; idx += 256) {
            int r = idx / 66, c = idx - r * 66;
            int gy = ty0 - 1 + r, gx = tx0 - 1 + c;
            float v = 0.f;
            if (gy >= 0 && gy < IMH && gx >= 0 && gx < IMW) v = img[gy * IMW + gx];
            esm[r][c] = v;
        }
        __syncthreads();
        int cy = t >> 4, cx = t & 15;
        double acc = 0.0;
        #pragma unroll
        for (int dy = 0; dy < 4; ++dy) {
            int py = cy * 4 + dy + 1;
            #pragma unroll
            for (int dx = 0; dx < 4; ++dx) {
                int px = cx * 4 + dx + 1;
                double a00 = (double)esm[py - 1][px - 1];
                double a01 = (double)esm[py - 1][px];
                double a02 = (double)esm[py - 1][px + 1];
                double a10 = (double)esm[py][px - 1];
                double a12 = (double)esm[py][px + 1];
                double a20 = (double)esm[py + 1][px - 1];
                double a21 = (double)esm[py + 1][px];
                double a22 = (double)esm[py + 1][px + 1];
                double sx = (a02 + 2.0 * a12 + a22) - (a00 + 2.0 * a10 + a20);
                double sy = (a20 + 2.0 * a21 + a22) - (a00 + 2.0 * a01 + a02);
                acc += sqrt(sx * sx + sy * sy);
            }
        }
        double cell = acc * (1.0 / 16.0);
        int gy = (ty0 >> 2) + cy;
        int gx = (tx0 >> 2) + cx;
        edges[((size_t)b << 14) + gy * 128 + gx] = cell;
        double sc = cell;
        #pragma unroll
        for (int off = 32; off > 0; off >>= 1) sc += __shfl_xor(sc, off);
        if (lane == 0) dred[wid] = sc;
        __syncthreads();
        if (t == 0) tsum[b * 64 + tile] = dred[0] + dred[1] + dred[2] + dred[3];
    }
}

// ---------------- Kernel 2: per-batch mask + half-row prefix (8 blocks) ----
// Coalesced edge reads; ballot -> one u64 per 64-cell half-row; 256-wide scan.
__global__ __launch_bounds__(256) void k_scan(const double* __restrict__ edges,
                                              const double* __restrict__ tsum,
                                              unsigned long long* __restrict__ halfbits,
                                              int* __restrict__ halfbase,
                                              int* __restrict__ Kout,
                                              float* __restrict__ mask_out) {
    int b = blockIdx.x;
    int t = threadIdx.x;
    int lane = t & 63, wid = t >> 6;
    __shared__ unsigned long long hb_s[256];
    __shared__ int wtot[4];

    // deterministic fixed-order fp64 mean (bit-identical to prior rounds)
    const double* ts = tsum + b * 64;
    double total = 0.0;
    #pragma unroll
    for (int j = 0; j < 64; ++j) total += ts[j];
    double mean = total * (1.0 / 16384.0);

    const double* e = edges + ((size_t)b << 14);
    float* mb = mask_out + ((size_t)b << 14);
    #pragma unroll 8
    for (int j = 0; j < 64; ++j) {
        double v = e[j * 256 + t];               // coalesced: lane stride 8B
        bool sel = v > mean;
        unsigned long long bal = __ballot(sel);  // bit l = cell j*256+w*64+l
        if (lane == 0) hb_s[j * 4 + wid] = bal;
        __builtin_nontemporal_store(sel ? 1.0f : 0.0f, mb + j * 256 + t);
    }
    __syncthreads();
    unsigned long long myb = hb_s[t];            // half-row t of this batch
    int cnt = __popcll(myb);
    int incl = cnt;
    #pragma unroll
    for (int off = 1; off < 64; off <<= 1) {
        int up = __shfl_up(incl, off);
        if (lane >= off) incl += up;
    }
    if (lane == 63) wtot[wid] = incl;
    __syncthreads();
    int woff = 0;
    #pragma unroll
    for (int w = 0; w < 4; ++w) { if (w < wid) woff += wtot[w]; }
    int excl = woff + incl - cnt;
    halfbits[b * 256 + t] = myb;
    halfbase[b * 256 + t] = excl;
    if (t == 255) Kout[b] = excl + cnt;
}

// ---------------- Kernel 3: fine embed, prelude-free ------------------------
// grid (256, 8): 64 patches (one half-row) per block, 256 threads.
__global__ __launch_bounds__(256) void k_fine(const float* __restrict__ x,
                                              const float* __restrict__ wfp,
                                              const float* __restrict__ bfp,
                                              const float* __restrict__ temb,
                                              const unsigned long long* __restrict__ halfbits,
                                              const int* __restrict__ halfbase,
                                              const int* __restrict__ Kout,
                                              float* __restrict__ out) {
    int b = blockIdx.y;
    int bx = blockIdx.x;                 // half-row index 0..255
    int t = threadIdx.x;
    __shared__ float smx[4][256];

    unsigned long long bits = halfbits[b * 256 + bx];
    int base = halfbase[b * 256 + bx];
    int K = Kout[b];

    int irow = (bx >> 1) * 4;            // image pixel row of this half-row
    int icol = (bx & 1) * 256;           // image pixel col offset
    const float* img = x + ((size_t)b * IMH + irow) * IMW + icol;
    {
        int r = t >> 6, c4 = t & 63;     // 4 rows x 64 float4
        *(float4*)&smx[r][c4 * 4] = *(const float4*)&img[r * IMW + c4 * 4];
    }
    __syncthreads();

    int d4 = t & 31;
    int g = t >> 5;
    float4 wcol[16];
    #pragma unroll
    for (int k = 0; k < 16; ++k) wcol[k] = *(const float4*)&wfp[k * ED + d4 * 4];
    float4 fill = *(const float4*)&temb[ED + d4 * 4];
    float4 bse = *(const float4*)&bfp[d4 * 4];
    float4 fbase = make_float4(bse.x + fill.x, bse.y + fill.y, bse.z + fill.z, bse.w + fill.w);
    float* tok = out + ((size_t)b * NTOK + NC) * ED;
    int i0 = bx * 64;
    #pragma unroll
    for (int pp = 0; pp < 8; ++pp) {
        int p = g + pp * 8;              // 0..63 within half-row
        int i = i0 + p;
        if ((bits >> p) & 1ULL) {
            int below = __popcll(bits & ((1ULL << p) - 1ULL));
            int ps = base + below;
            float4 acc = fbase;
            #pragma unroll
            for (int r = 0; r < 4; ++r) {
                float4 vv = *(const float4*)&smx[r][p * 4];
                acc.x += vv.x * wcol[4 * r].x + vv.y * wcol[4 * r + 1].x + vv.z * wcol[4 * r + 2].x + vv.w * wcol[4 * r + 3].x;
                acc.y += vv.x * wcol[4 * r].y + vv.y * wcol[4 * r + 1].y + vv.z * wcol[4 * r + 2].y + vv.w * wcol[4 * r + 3].y;
                acc.z += vv.x * wcol[4 * r].z + vv.y * wcol[4 * r + 1].z + vv.z * wcol[4 * r + 2].z + vv.w * wcol[4 * r + 3].z;
                acc.w += vv.x * wcol[4 * r].w + vv.y * wcol[4 * r + 1].w + vv.z * wcol[4 * r + 2].w + vv.w * wcol[4 * r + 3].w;
            }
            nt_store4v(tok + ((size_t)ps * 32 + d4) * 4, acc);
        }
        if (i >= K) {
            nt_store4v(tok + ((size_t)i * 32 + d4) * 4, fill);
        }
    }
}

extern "C" void kernel_launch(void* const* d_in, const int* in_sizes, int n_in,
                              void* d_out, int out_size, void* d_ws, size_t ws_size,
                              hipStream_t stream) {
    const float* x    = (const float*)d_in[0];
    const float* wc   = (const float*)d_in[1];
    const float* bc   = (const float*)d_in[2];
    const float* wfp  = (const float*)d_in[3];
    const float* bfp  = (const float*)d_in[4];
    const float* temb = (const float*)d_in[5];
    float* out = (float*)d_out;

    char* wsb = (char*)d_ws;
    double* edges = (double*)wsb;                                         // 1 MiB
    double* tsum  = (double*)(wsb + (size_t)BATCH * NF * 8);              // 4 KiB
    unsigned long long* halfbits = (unsigned long long*)(wsb + (size_t)BATCH * NF * 8 + 4096);  // 16 KiB
    int* halfbase = (int*)(wsb + (size_t)BATCH * NF * 8 + 4096 + 16384);  // 8 KiB
    int* Kout     = (int*)(wsb + (size_t)BATCH * NF * 8 + 4096 + 16384 + 8192);
    float* mask_out = out + (size_t)BATCH * NTOK * ED;

    k1_edge_coarse<<<dim3(1536), 256, 0, stream>>>(x, wc, bc, temb, out, edges, tsum);
    k_scan<<<dim3(BATCH), 256, 0, stream>>>(edges, tsum, halfbits, halfbase, Kout, mask_out);
    k_fine<<<dim3(256, BATCH), 256, 0, stream>>>(x, wfp, bfp, temb, halfbits, halfbase, Kout, out);
}

// Round 11
// 54.678 us; speedup vs baseline: 5.6304x; 1.0746x over previous
//
#include <hip/hip_runtime.h>

#define IMH 512
#define IMW 512
#define BATCH 8
#define NTOK 20480
#define NC 4096
#define NF 16384
#define ED 128

// ---------------- Kernel 1: edge map (512 blocks) --------------------------
__global__ __launch_bounds__(256) void k_edge(const float* __restrict__ x,
                                              double* __restrict__ edges,
                                              double* __restrict__ tsum) {
    __shared__ float esm[66][68];
    __shared__ double dred[4];
    int blk = blockIdx.x;
    int t = threadIdx.x;
    int lane = t & 63, wid = t >> 6;
    int b = blk >> 6;
    int tile = blk & 63;
    int ty0 = (tile >> 3) * 64;
    int tx0 = (tile & 7) * 64;
    const float* img = x + (size_t)b * (IMH * IMW);
    for (int idx = t; idx < 66 * 66; idx += 256) {
        int r = idx / 66, c = idx - r * 66;
        int gy = ty0 - 1 + r, gx = tx0 - 1 + c;
        float v = 0.f;
        if (gy >= 0 && gy < IMH && gx >= 0 && gx < IMW) v = img[gy * IMW + gx];
        esm[r][c] = v;
    }
    __syncthreads();
    int cy = t >> 4, cx = t & 15;
    double acc = 0.0;
    #pragma unroll
    for (int dy = 0; dy < 4; ++dy) {
        int py = cy * 4 + dy + 1;
        #pragma unroll
        for (int dx = 0; dx < 4; ++dx) {
            int px = cx * 4 + dx + 1;
            double a00 = (double)esm[py - 1][px - 1];
            double a01 = (double)esm[py - 1][px];
            double a02 = (double)esm[py - 1][px + 1];
            double a10 = (double)esm[py][px - 1];
            double a12 = (double)esm[py][px + 1];
            double a20 = (double)esm[py + 1][px - 1];
            double a21 = (double)esm[py + 1][px];
            double a22 = (double)esm[py + 1][px + 1];
            double sx = (a02 + 2.0 * a12 + a22) - (a00 + 2.0 * a10 + a20);
            double sy = (a20 + 2.0 * a21 + a22) - (a00 + 2.0 * a01 + a02);
            acc += sqrt(sx * sx + sy * sy);
        }
    }
    double cell = acc * (1.0 / 16.0);
    int gy = (ty0 >> 2) + cy;
    int gx = (tx0 >> 2) + cx;
    edges[((size_t)b << 14) + gy * 128 + gx] = cell;
    double sc = cell;
    #pragma unroll
    for (int off = 32; off > 0; off >>= 1) sc += __shfl_xor(sc, off);
    if (lane == 0) dred[wid] = sc;
    __syncthreads();
    if (t == 0) tsum[b * 64 + tile] = dred[0] + dred[1] + dred[2] + dred[3];
}

// ---------------- Kernel 2: per-batch mean, mask, prefix scan --------------
// one block per batch, 1024 threads, 16 cells/thread (R5-proven structure)
__global__ __launch_bounds__(1024) void k_scan(const double* __restrict__ edges,
                                               const double* __restrict__ tsum,
                                               int* __restrict__ pos,
                                               int* __restrict__ Karr,
                                               float* __restrict__ mask_out) {
    int b = blockIdx.x;
    int t = threadIdx.x;
    int lane = t & 63, wid = t >> 6;
    __shared__ int wcnt[16];
    // deterministic fixed-order fp64 mean (bit-identical across rounds)
    const double* ts = tsum + b * 64;
    double total = 0.0;
    #pragma unroll
    for (int j = 0; j < 64; ++j) total += ts[j];
    double mean = total * (1.0 / 16384.0);

    const double* e = edges + ((size_t)b << 14);
    double v[16];
    #pragma unroll
    for (int j = 0; j < 8; ++j) {
        double2 dv = *(const double2*)&e[t * 16 + j * 2];
        v[2 * j] = dv.x; v[2 * j + 1] = dv.y;
    }
    int m[16], cnt = 0;
    #pragma unroll
    for (int j = 0; j < 16; ++j) { m[j] = (v[j] > mean) ? 1 : 0; cnt += m[j]; }
    int incl = cnt;
    #pragma unroll
    for (int off = 1; off < 64; off <<= 1) {
        int up = __shfl_up(incl, off);
        if (lane >= off) incl += up;
    }
    if (lane == 63) wcnt[wid] = incl;
    __syncthreads();
    int woff = 0, Ktot = 0;
    #pragma unroll
    for (int w = 0; w < 16; ++w) { int c = wcnt[w]; Ktot += c; if (w < wid) woff += c; }
    int run = woff + incl - cnt;
    float mf[16]; int pv[16];
    #pragma unroll
    for (int j = 0; j < 16; ++j) {
        pv[j] = m[j] ? run : -1;
        run += m[j];
        mf[j] = m[j] ? 1.0f : 0.0f;
    }
    float* mb = mask_out + ((size_t)b << 14) + t * 16;
    int* pb = pos + ((size_t)b << 14) + t * 16;
    #pragma unroll
    for (int q = 0; q < 4; ++q) {
        *(float4*)&mb[q * 4] = make_float4(mf[4 * q], mf[4 * q + 1], mf[4 * q + 2], mf[4 * q + 3]);
        *(int4*)&pb[q * 4] = make_int4(pv[4 * q], pv[4 * q + 1], pv[4 * q + 2], pv[4 * q + 3]);
    }
    if (t == 0) Karr[b] = Ktot;
}

// ---------------- Kernel 3: mega token writer (1024 blocks) ----------------
// Each block: 32 coarse patches (wave-uniform scalar loads) + 2 fine units
// of 64 patches. ALL stores regular (L2 write-combining), no NT.
__global__ __launch_bounds__(256) void k_mega(const float* __restrict__ x,
                                              const float* __restrict__ wc,
                                              const float* __restrict__ bc,
                                              const float* __restrict__ wfp,
                                              const float* __restrict__ bfp,
                                              const float* __restrict__ temb,
                                              const int* __restrict__ pos,
                                              const int* __restrict__ Karr,
                                              float* __restrict__ out) {
    __shared__ float smx[4][256];
    int blk = blockIdx.x;
    int t = threadIdx.x;
    int lane = t & 63;
    int b = blk >> 7;
    int r128 = blk & 127;

    // ---- coarse part: 32 patches, wave-uniform scalar loads, no LDS ----
    {
        int pblk = r128 * 32;
        int wv = __builtin_amdgcn_readfirstlane(t >> 6);  // wave id 0..3
        int h = wv & 1;
        int p0 = pblk + (wv >> 1) * 16;
        int d = h * 64 + lane;
        float wcol[64];
        #pragma unroll
        for (int k = 0; k < 64; ++k) wcol[k] = wc[k * ED + d];
        float base = bc[d] + temb[d];
        const float* img = x + ((size_t)b * IMH + (p0 >> 6) * 8) * IMW + (p0 & 63) * 8;
        float* dst = out + ((size_t)b * NTOK + p0) * ED + d;
        #pragma unroll
        for (int p = 0; p < 16; ++p) {
            const float* pimg = img + p * 8;    // wave-uniform -> scalar loads
            float acc = base;
            #pragma unroll
            for (int r = 0; r < 8; ++r) {
                const float* rp = pimg + r * IMW;
                acc += rp[0] * wcol[r * 8 + 0] + rp[1] * wcol[r * 8 + 1]
                     + rp[2] * wcol[r * 8 + 2] + rp[3] * wcol[r * 8 + 3]
                     + rp[4] * wcol[r * 8 + 4] + rp[5] * wcol[r * 8 + 5]
                     + rp[6] * wcol[r * 8 + 6] + rp[7] * wcol[r * 8 + 7];
            }
            dst[(size_t)p * ED] = acc;
        }
    }
    asm volatile("" ::: "memory");

    // ---- fine part: 2 units of 64 patches each ----
    int d4 = t & 31;
    int g = t >> 5;
    float4 wcol[16];
    #pragma unroll
    for (int k = 0; k < 16; ++k) wcol[k] = *(const float4*)&wfp[k * ED + d4 * 4];
    float4 fill = *(const float4*)&temb[ED + d4 * 4];
    float4 bse = *(const float4*)&bfp[d4 * 4];
    float4 fbase = make_float4(bse.x + fill.x, bse.y + fill.y, bse.z + fill.z, bse.w + fill.w);
    int K = Karr[b];
    const int* posb = pos + ((size_t)b << 14);
    float* tok = out + ((size_t)b * NTOK + NC) * ED;

    #pragma unroll
    for (int u = 0; u < 2; ++u) {
        int i0 = (r128 * 2 + u) * 64;
        int hf = i0 >> 7;                  // fine patch-row
        int wf0 = i0 & 127;                // fine patch-col offset
        const float* img = x + ((size_t)b * IMH + hf * 4) * IMW + wf0 * 4;
        __syncthreads();
        {
            int r = t >> 6, c4 = t & 63;   // 4 rows x 64 float4
            *(float4*)&smx[r][c4 * 4] = *(const float4*)&img[r * IMW + c4 * 4];
        }
        __syncthreads();
        #pragma unroll
        for (int pp = 0; pp < 8; ++pp) {
            int p = g + pp * 8;
            int i = i0 + p;
            int ps = posb[i];
            if (ps >= 0) {
                float4 acc = fbase;
                #pragma unroll
                for (int r = 0; r < 4; ++r) {
                    float4 vv = *(const float4*)&smx[r][p * 4];
                    acc.x += vv.x * wcol[4 * r].x + vv.y * wcol[4 * r + 1].x + vv.z * wcol[4 * r + 2].x + vv.w * wcol[4 * r + 3].x;
                    acc.y += vv.x * wcol[4 * r].y + vv.y * wcol[4 * r + 1].y + vv.z * wcol[4 * r + 2].y + vv.w * wcol[4 * r + 3].y;
                    acc.z += vv.x * wcol[4 * r].z + vv.y * wcol[4 * r + 1].z + vv.z * wcol[4 * r + 2].z + vv.w * wcol[4 * r + 3].z;
                    acc.w += vv.x * wcol[4 * r].w + vv.y * wcol[4 * r + 1].w + vv.z * wcol[4 * r + 2].w + vv.w * wcol[4 * r + 3].w;
                }
                *(float4*)(tok + ((size_t)ps * 32 + d4) * 4) = acc;
            }
            if (i >= K) {
                *(float4*)(tok + ((size_t)i * 32 + d4) * 4) = fill;
            }
        }
    }
}

extern "C" void kernel_launch(void* const* d_in, const int* in_sizes, int n_in,
                              void* d_out, int out_size, void* d_ws, size_t ws_size,
                              hipStream_t stream) {
    const float* x    = (const float*)d_in[0];
    const float* wc   = (const float*)d_in[1];
    const float* bc   = (const float*)d_in[2];
    const float* wfp  = (const float*)d_in[3];
    const float* bfp  = (const float*)d_in[4];
    const float* temb = (const float*)d_in[5];
    float* out = (float*)d_out;

    char* wsb = (char*)d_ws;
    double* edges = (double*)wsb;                                   // 1 MiB
    double* tsum  = (double*)(wsb + (size_t)BATCH * NF * 8);        // 4 KiB
    int* pos  = (int*)(wsb + (size_t)BATCH * NF * 8 + 4096);        // 512 KiB
    int* Karr = (int*)(wsb + (size_t)BATCH * NF * 8 + 4096 + (size_t)BATCH * NF * 4);
    float* mask_out = out + (size_t)BATCH * NTOK * ED;

    k_edge<<<dim3(512), 256, 0, stream>>>(x, edges, tsum);
    k_scan<<<dim3(BATCH), 1024, 0, stream>>>(edges, tsum, pos, Karr, mask_out);
    k_mega<<<dim3(1024), 256, 0, stream>>>(x, wc, bc, wfp, bfp, temb, pos, Karr, out);
}